// Round 4
// baseline (469.850 us; speedup 1.0000x reference)
//
#include <hip/hip_runtime.h>
#include <hip/hip_bf16.h>
#include <math.h>

#define BB 2
#define QQ 300
#define TT 300
#define HH 256
#define WW 256
#define PP 12544
#define NCHUNK 16                 // 16-row y-buckets
#define PBLK (PP / 256)           // 49 blocks per batch for prep/scatter

typedef __bf16 bf16_t;
typedef bf16_t bf16x8 __attribute__((ext_vector_type(8)));
typedef float floatx4 __attribute__((ext_vector_type(4)));

__device__ inline void gl_lds16(const void* g, void* l) {
    __builtin_amdgcn_global_load_lds(
        (const __attribute__((address_space(1))) unsigned int*)g,
        (__attribute__((address_space(3))) unsigned int*)l, 16, 0, 0);
}

// ---------------- kernel 1: bilinear offsets/weights + bucket + histogram ----------------
__global__ __launch_bounds__(256) void prep_kernel(const float* __restrict__ pts,
                                                   int4* __restrict__ off,
                                                   float4* __restrict__ wgt,
                                                   int* __restrict__ bkt,
                                                   int* __restrict__ hist) {
    __shared__ int lh[NCHUNK];
    int tid = threadIdx.x;
    if (tid < NCHUNK) lh[tid] = 0;
    __syncthreads();
    int idx = blockIdx.x * 256 + tid;          // grid is exactly BB*PP/256 = 98 blocks
    int b = blockIdx.x / PBLK;
    float px = pts[idx * 2 + 0];
    float py = pts[idx * 2 + 1];
    float x = px * WW - 0.5f;
    float y = py * HH - 0.5f;
    float x0f = floorf(x), y0f = floorf(y);
    float wx = x - x0f, wy = y - y0f;
    int x0 = (int)x0f, y0 = (int)y0f;
    int x1 = x0 + 1, y1 = y0 + 1;
    float vx0 = (x0 >= 0 && x0 < WW) ? 1.f : 0.f;
    float vx1 = (x1 >= 0 && x1 < WW) ? 1.f : 0.f;
    float vy0 = (y0 >= 0 && y0 < HH) ? 1.f : 0.f;
    float vy1 = (y1 >= 0 && y1 < HH) ? 1.f : 0.f;
    int cx0 = min(max(x0, 0), WW - 1), cx1 = min(max(x1, 0), WW - 1);
    int cy0 = min(max(y0, 0), HH - 1), cy1 = min(max(y1, 0), HH - 1);
    off[idx] = make_int4(cy0 * WW + cx0, cy0 * WW + cx1, cy1 * WW + cx0, cy1 * WW + cx1);
    wgt[idx] = make_float4((1.f - wy) * (1.f - wx) * vy0 * vx0,
                           (1.f - wy) * wx        * vy0 * vx1,
                           wy        * (1.f - wx) * vy1 * vx0,
                           wy        * wx         * vy1 * vx1);
    int k = min(max(y0, 0), HH - 2) >> 4;      // rows y0,y0+1 in [16k, 16k+16]
    bkt[idx] = k;
    atomicAdd(&lh[k], 1);
    __syncthreads();
    if (tid < NCHUNK && lh[tid] > 0) atomicAdd(&hist[b * NCHUNK + tid], lh[tid]);
}

// ---------------- kernel 1b: 16-entry prefix scan per batch (tiny) ----------------
__global__ void scan_kernel(const int* __restrict__ hist, int* __restrict__ cs,
                            int* __restrict__ ctr) {
    int b = threadIdx.x;
    if (b < BB) {
        int run = 0;
        for (int k = 0; k < NCHUNK; ++k) {
            cs[b * (NCHUNK + 1) + k] = run;
            ctr[b * NCHUNK + k] = run;
            run += hist[b * NCHUNK + k];
        }
        cs[b * (NCHUNK + 1) + NCHUNK] = run;   // == PP
    }
}

// ---------------- kernel 1c: parallel scatter into buckets ----------------
__global__ __launch_bounds__(256) void scatter_kernel(const int4* __restrict__ off,
                                                      const float4* __restrict__ wgt,
                                                      const int* __restrict__ bkt,
                                                      int* __restrict__ ctr,
                                                      int4* __restrict__ off_s,
                                                      float4* __restrict__ wgt_s) {
    __shared__ int lh[NCHUNK];
    __shared__ int lbase[NCHUNK];
    int tid = threadIdx.x;
    if (tid < NCHUNK) lh[tid] = 0;
    __syncthreads();
    int idx = blockIdx.x * 256 + tid;          // = b*PP + p exactly
    int b = blockIdx.x / PBLK;
    int k = bkt[idx];
    int rank = atomicAdd(&lh[k], 1);
    __syncthreads();
    if (tid < NCHUNK) lbase[tid] = (lh[tid] > 0) ? atomicAdd(&ctr[b * NCHUNK + tid], lh[tid]) : 0;
    __syncthreads();
    int pos = lbase[k] + rank;
    off_s[b * PP + pos] = off[idx];
    wgt_s[b * PP + pos] = wgt[idx];
}

// ---------------- kernel 2: point-sample, L2-direct gather (no LDS staging) ----------------
// Each (mask, chunk) window is 17 KB (L1-scale), each image 256 KB (L2-scale),
// all images 153 MB (L3-fits): stage-and-drain was pure overhead (guide CM#7).
// Depth-2 software pipeline: offsets 2 iters ahead, pixels 1 iter ahead, all
// named registers (no arrays -> no scratch).
__global__ __launch_bounds__(256) void sample_kernel(
    const float* __restrict__ pred_masks, const float* __restrict__ tgt_masks,
    const int4* __restrict__ off_s, const float4* __restrict__ wgt_s,
    const int* __restrict__ cs_g,
    bf16_t* __restrict__ OM, bf16_t* __restrict__ SM, bf16_t* __restrict__ TM,
    float* __restrict__ RS_SP, float* __restrict__ RS_S, float* __restrict__ RS_T) {
    int b = blockIdx.z;
    int m = blockIdx.x;  // 0..QQ+TT-1
    int c = blockIdx.y;  // chunk
    int tid = threadIdx.x;
    int wave = tid >> 6, lane = tid & 63;
    __shared__ float ra_[4], rb_[4];

    bool is_pred = (m < QQ);
    const float* img;
    bf16_t* row0;
    bf16_t* row1 = nullptr;
    if (is_pred) {
        img  = pred_masks + (size_t)(b * QQ + m) * (HH * WW);
        row0 = OM + (size_t)(b * QQ + m) * PP;
        row1 = SM + (size_t)(b * QQ + m) * PP;
    } else {
        int t = m - QQ;
        img  = tgt_masks + (size_t)(b * TT + t) * (HH * WW);
        row0 = TM + (size_t)(b * TT + t) * PP;
    }

    const int4*   offb = off_s + b * PP;
    const float4* wb   = wgt_s + b * PP;
    const int*    cs   = cs_g + b * (NCHUNK + 1);
    int j1 = cs[c + 1];
    float s0 = 0.f, s1 = 0.f;

    int j = cs[c] + tid;
    int4 o0, o1; float4 w0, w1;
    float p00, p01, p10, p11;
    if (j < j1) {
        o0 = offb[j]; w0 = wb[j];
        p00 = img[o0.x]; p01 = img[o0.y]; p10 = img[o0.z]; p11 = img[o0.w];
    }
    if (j + 256 < j1) { o1 = offb[j + 256]; w1 = wb[j + 256]; }

    while (j < j1) {
        int jn = j + 256;
        int4 o2; float4 w2;
        float q00, q01, q10, q11;
        if (jn + 256 < j1) { o2 = offb[jn + 256]; w2 = wb[jn + 256]; }   // offs 2 ahead
        if (jn < j1) {                                                   // pixels 1 ahead
            q00 = img[o1.x]; q01 = img[o1.y]; q10 = img[o1.z]; q11 = img[o1.w];
        }
        float v = w0.x * p00 + w0.y * p01 + w0.z * p10 + w0.w * p11;
        row0[j] = (bf16_t)v;
        if (is_pred) {
            float e = __expf(-fabsf(v));
            float r = 1.f / (1.f + e);
            float sg = (v >= 0.f) ? r : e * r;
            row1[j] = (bf16_t)sg;
            s0 += fmaxf(v, 0.f) + __logf(1.f + e);   // stable softplus
            s1 += sg;
        } else {
            s0 += v;
        }
        o0 = o1; w0 = w1; o1 = o2; w1 = w2;
        p00 = q00; p01 = q01; p10 = q10; p11 = q11;
        j = jn;
    }

    for (int sh = 32; sh > 0; sh >>= 1) {
        s0 += __shfl_down(s0, sh, 64);
        s1 += __shfl_down(s1, sh, 64);
    }
    if (lane == 0) { ra_[wave] = s0; rb_[wave] = s1; }
    __syncthreads();
    if (tid == 0) {
        float t0 = ra_[0] + ra_[1] + ra_[2] + ra_[3];
        float t1 = rb_[0] + rb_[1] + rb_[2] + rb_[3];
        if (is_pred) {
            atomicAdd(&RS_SP[b * QQ + m], t0);
            atomicAdd(&RS_S[b * QQ + m], t1);
        } else {
            atomicAdd(&RS_T[b * TT + (m - QQ)], t0);
        }
    }
}

// ---------------- kernel 3: 128x128 dual bf16 MFMA GEMM, split-K ----------------
template<int NS>
__global__ __launch_bounds__(512) void matmul_kernel(
    const bf16_t* __restrict__ OM, const bf16_t* __restrict__ SM, const bf16_t* __restrict__ TM,
    float* __restrict__ A1P, float* __restrict__ A2P) {
    constexpr int KSP = PP / NS;          // 448 (NS=28) or 896 (NS=14)
    constexpr int KST = KSP / 64;
    static_assert(KSP % 64 == 0, "K split must be a multiple of 64");
    int b = blockIdx.z / NS;
    int split = blockIdx.z % NS;
    int m0 = blockIdx.x * 128;
    int n0 = blockIdx.y * 128;
    int tid = threadIdx.x;
    int wave = tid >> 6, lane = tid & 63;
    int lrow = lane & 15, quad = lane >> 4;
    int wm = wave & 3;                     // m-quarter (32 rows)
    int wn = wave >> 2;                    // n-half (64 cols)

    __shared__ __align__(16) bf16_t lds[3 * 128 * 64];   // [A1 | A2 | B], 48 KB

    int k0 = split * KSP;
    int lr8 = lane >> 3;           // row within 8-row group
    int clog = (lane & 7) ^ lr8;   // swizzled logical chunk this lane fetches

    const char* gp[6];
    unsigned lofs[6];
#pragma unroll
    for (int jj = 0; jj < 6; ++jj) {
        int L = wave + jj * 8;     // 48 wave-loads: 3 matrices x 16 row-groups
        int mat = L >> 4, i = L & 15;
        int rb_ = (mat == 2) ? n0 : m0;
        int row = min(rb_ + i * 8 + lr8, (mat == 2) ? (TT - 1) : (QQ - 1));
        const bf16_t* g = (mat == 0) ? OM + (size_t)b * QQ * PP
                        : (mat == 1) ? SM + (size_t)b * QQ * PP
                                     : TM + (size_t)b * TT * PP;
        gp[jj] = (const char*)(g + (size_t)row * PP + k0) + clog * 16;
        lofs[jj] = mat * 8192 + i * 512;   // 8 rows x 64 bf16 per group
    }

    floatx4 acc1[2][4], acc2[2][4];
#pragma unroll
    for (int r = 0; r < 2; ++r)
#pragma unroll
        for (int j = 0; j < 4; ++j) {
            acc1[r][j] = (floatx4){0.f, 0.f, 0.f, 0.f};
            acc2[r][j] = (floatx4){0.f, 0.f, 0.f, 0.f};
        }

    int ar0 = wm * 32 + lrow;              // first 16-row frag
    int ar1 = ar0 + 16;                    // second 16-row frag
    int ax0 = ar0 & 7, ax1 = ar1 & 7;
    for (int s = 0; s < KST; ++s) {
#pragma unroll
        for (int jj = 0; jj < 6; ++jj) {
            gl_lds16(gp[jj], lds + lofs[jj]);
            gp[jj] += 128;   // 64 bf16
        }
        __syncthreads();
#pragma unroll
        for (int kk8 = 0; kk8 <= 4; kk8 += 4) {   // two K=32 halves of BK=64
            bf16x8 a1_0 = *(const bf16x8*)(lds + ar0 * 64 + (((quad + kk8) ^ ax0) << 3));
            bf16x8 a1_1 = *(const bf16x8*)(lds + ar1 * 64 + (((quad + kk8) ^ ax1) << 3));
            bf16x8 a2_0 = *(const bf16x8*)(lds + 8192 + ar0 * 64 + (((quad + kk8) ^ ax0) << 3));
            bf16x8 a2_1 = *(const bf16x8*)(lds + 8192 + ar1 * 64 + (((quad + kk8) ^ ax1) << 3));
#pragma unroll
            for (int j = 0; j < 4; ++j) {
                int br = wn * 64 + j * 16 + lrow;
                bf16x8 vb = *(const bf16x8*)(lds + 16384 + br * 64 + (((quad + kk8) ^ (br & 7)) << 3));
                acc1[0][j] = __builtin_amdgcn_mfma_f32_16x16x32_bf16(a1_0, vb, acc1[0][j], 0, 0, 0);
                acc1[1][j] = __builtin_amdgcn_mfma_f32_16x16x32_bf16(a1_1, vb, acc1[1][j], 0, 0, 0);
                acc2[0][j] = __builtin_amdgcn_mfma_f32_16x16x32_bf16(a2_0, vb, acc2[0][j], 0, 0, 0);
                acc2[1][j] = __builtin_amdgcn_mfma_f32_16x16x32_bf16(a2_1, vb, acc2[1][j], 0, 0, 0);
            }
        }
        __syncthreads();
    }

    // C/D layout: col = lane&15, row = quad*4 + reg
    float* o1 = A1P + (size_t)(b * NS + split) * (QQ * TT);
    float* o2 = A2P + (size_t)(b * NS + split) * (QQ * TT);
#pragma unroll
    for (int r16 = 0; r16 < 2; ++r16) {
        int mrow = m0 + wm * 32 + r16 * 16 + quad * 4;
#pragma unroll
        for (int j = 0; j < 4; ++j) {
            int n = n0 + wn * 64 + j * 16 + lrow;
            if (n < TT) {
#pragma unroll
                for (int r = 0; r < 4; ++r) {
                    int mm = mrow + r;
                    if (mm < QQ) {
                        o1[mm * TT + n] = acc1[r16][j][r];
                        o2[mm * TT + n] = acc2[r16][j][r];
                    }
                }
            }
        }
    }
}

// ---------------- kernel 4: reduce splits + mask/dice/bbox/giou combine ----------------
template<int NS>
__global__ __launch_bounds__(256) void combine_kernel(
    const float* __restrict__ A1P, const float* __restrict__ A2P,
    const float* __restrict__ RS_SP, const float* __restrict__ RS_S, const float* __restrict__ RS_T,
    const float* __restrict__ pred_boxes, const float* __restrict__ tgt_boxes,
    float* __restrict__ out) {
    int idx = blockIdx.x * 256 + threadIdx.x;
    if (idx >= BB * QQ * TT) return;
    int b = idx / (QQ * TT);
    int r = idx - b * (QQ * TT);
    int q = r / TT;
    int t = r - q * TT;

    float a1 = 0.f, a2 = 0.f;
    for (int s = 0; s < NS; ++s) {
        a1 += A1P[(size_t)(b * NS + s) * (QQ * TT) + r];
        a2 += A2P[(size_t)(b * NS + s) * (QQ * TT) + r];
    }
    float cm = (RS_SP[b * QQ + q] - a1) * (1.0f / (float)PP);
    float cd = 1.f - (2.f * a2 + 1.f) / (RS_S[b * QQ + q] + RS_T[b * TT + t] + 1.f);

    const float* pb = pred_boxes + (size_t)(b * QQ + q) * 4;
    const float* tb = tgt_boxes + (size_t)(b * TT + t) * 4;
    float cb = fabsf(pb[0] - tb[0]) + fabsf(pb[1] - tb[1]) +
               fabsf(pb[2] - tb[2]) + fabsf(pb[3] - tb[3]);

    float ax0 = pb[0] - 0.5f * pb[2], ay0 = pb[1] - 0.5f * pb[3];
    float ax1 = pb[0] + 0.5f * pb[2], ay1 = pb[1] + 0.5f * pb[3];
    float bx0 = tb[0] - 0.5f * tb[2], by0 = tb[1] - 0.5f * tb[3];
    float bx1 = tb[0] + 0.5f * tb[2], by1 = tb[1] + 0.5f * tb[3];
    float area_a = (ax1 - ax0) * (ay1 - ay0);
    float area_b = (bx1 - bx0) * (by1 - by0);
    float iw = fmaxf(fminf(ax1, bx1) - fmaxf(ax0, bx0), 0.f);
    float ih = fmaxf(fminf(ay1, by1) - fmaxf(ay0, by0), 0.f);
    float inter = iw * ih;
    float uni = area_a + area_b - inter;
    float iou = inter / uni;
    float ew = fmaxf(ax1, bx1) - fminf(ax0, bx0);
    float eh = fmaxf(ay1, by1) - fminf(ay0, by0);
    float area_e = ew * eh;
    float giou = iou - (area_e - uni) / area_e;

    out[idx] = 5.f * cm + 5.f * cd + 5.f * cb - 2.f * giou;
}

extern "C" void kernel_launch(void* const* d_in, const int* in_sizes, int n_in,
                              void* d_out, int out_size, void* d_ws, size_t ws_size,
                              hipStream_t stream) {
    const float* pred_masks = (const float*)d_in[0];
    const float* tgt_masks  = (const float*)d_in[1];
    const float* pred_boxes = (const float*)d_in[2];
    const float* tgt_boxes  = (const float*)d_in[3];
    const float* pts        = (const float*)d_in[4];

    char* w = (char*)d_ws;
    auto alloc = [&](size_t bytes) -> char* {
        char* r = w;
        w += (bytes + 255) & ~(size_t)255;
        return r;
    };
    int4*   OFF   = (int4*)  alloc((size_t)BB * PP * sizeof(int4));
    float4* WGT   = (float4*)alloc((size_t)BB * PP * sizeof(float4));
    int*    BKT   = (int*)   alloc((size_t)BB * PP * sizeof(int));
    int4*   OFF_S = (int4*)  alloc((size_t)BB * PP * sizeof(int4));
    float4* WGT_S = (float4*)alloc((size_t)BB * PP * sizeof(float4));
    int*    CS    = (int*)   alloc((size_t)BB * (NCHUNK + 1) * sizeof(int));
    bf16_t* OM    = (bf16_t*)alloc((size_t)BB * QQ * PP * 2);
    bf16_t* SM    = (bf16_t*)alloc((size_t)BB * QQ * PP * 2);
    bf16_t* TM    = (bf16_t*)alloc((size_t)BB * TT * PP * 2);
    float*  RS_SP = (float*) alloc((size_t)BB * QQ * 4);
    float*  RS_S  = (float*) alloc((size_t)BB * QQ * 4);
    float*  RS_T  = (float*) alloc((size_t)BB * TT * 4);
    int*    HIST  = (int*)   alloc((size_t)BB * NCHUNK * sizeof(int));
    int*    CTR   = (int*)   alloc((size_t)BB * NCHUNK * sizeof(int));

    // choose split-K factor based on remaining workspace (28 needs +20 MB vs 14)
    size_t used = (size_t)(w - (char*)d_ws);
    size_t per_arr28 = (size_t)BB * 28 * QQ * TT * 4;
    int NS = (ws_size >= used + 2 * per_arr28 + 4096) ? 28 : 14;
    float* A1P = (float*)alloc((size_t)BB * NS * QQ * TT * 4);
    float* A2P = (float*)alloc((size_t)BB * NS * QQ * TT * 4);

    // zero atomic accumulators + histograms (RS_SP..CTR incl. padding)
    hipMemsetAsync(RS_SP, 0, (size_t)((char*)A1P - (char*)RS_SP), stream);

    prep_kernel<<<BB * PBLK, 256, 0, stream>>>(pts, OFF, WGT, BKT, HIST);
    scan_kernel<<<1, 64, 0, stream>>>(HIST, CS, CTR);
    scatter_kernel<<<BB * PBLK, 256, 0, stream>>>(OFF, WGT, BKT, CTR, OFF_S, WGT_S);
    sample_kernel<<<dim3(QQ + TT, NCHUNK, BB), 256, 0, stream>>>(
        pred_masks, tgt_masks, OFF_S, WGT_S, CS, OM, SM, TM, RS_SP, RS_S, RS_T);
    if (NS == 28) {
        matmul_kernel<28><<<dim3(3, 3, BB * 28), 512, 0, stream>>>(OM, SM, TM, A1P, A2P);
        combine_kernel<28><<<(BB * QQ * TT + 255) / 256, 256, 0, stream>>>(
            A1P, A2P, RS_SP, RS_S, RS_T, pred_boxes, tgt_boxes, (float*)d_out);
    } else {
        matmul_kernel<14><<<dim3(3, 3, BB * 14), 512, 0, stream>>>(OM, SM, TM, A1P, A2P);
        combine_kernel<14><<<(BB * QQ * TT + 255) / 256, 256, 0, stream>>>(
            A1P, A2P, RS_SP, RS_S, RS_T, pred_boxes, tgt_boxes, (float*)d_out);
    }
}

// Round 5
// 374.862 us; speedup vs baseline: 1.2534x; 1.2534x over previous
//
#include <hip/hip_runtime.h>
#include <hip/hip_bf16.h>
#include <math.h>

#define BB 2
#define QQ 300
#define TT 300
#define HH 256
#define WW 256
#define PP 12544
#define NCHUNK 16                 // 16-row y-buckets
#define PBLK (PP / 256)           // 49 blocks per batch for prep/scatter

typedef __bf16 bf16_t;
typedef bf16_t bf16x8 __attribute__((ext_vector_type(8)));
typedef float floatx4 __attribute__((ext_vector_type(4)));

__device__ inline void gl_lds16(const void* g, void* l) {
    __builtin_amdgcn_global_load_lds(
        (const __attribute__((address_space(1))) unsigned int*)g,
        (__attribute__((address_space(3))) unsigned int*)l, 16, 0, 0);
}

// ---------------- kernel 1: bilinear offsets/weights + bucket + histogram ----------------
__global__ __launch_bounds__(256) void prep_kernel(const float* __restrict__ pts,
                                                   int4* __restrict__ off,
                                                   float4* __restrict__ wgt,
                                                   int* __restrict__ bkt,
                                                   int* __restrict__ hist) {
    __shared__ int lh[NCHUNK];
    int tid = threadIdx.x;
    if (tid < NCHUNK) lh[tid] = 0;
    __syncthreads();
    int idx = blockIdx.x * 256 + tid;          // grid is exactly BB*PP/256 = 98 blocks
    int b = blockIdx.x / PBLK;
    float px = pts[idx * 2 + 0];
    float py = pts[idx * 2 + 1];
    float x = px * WW - 0.5f;
    float y = py * HH - 0.5f;
    float x0f = floorf(x), y0f = floorf(y);
    float wx = x - x0f, wy = y - y0f;
    int x0 = (int)x0f, y0 = (int)y0f;
    int x1 = x0 + 1, y1 = y0 + 1;
    float vx0 = (x0 >= 0 && x0 < WW) ? 1.f : 0.f;
    float vx1 = (x1 >= 0 && x1 < WW) ? 1.f : 0.f;
    float vy0 = (y0 >= 0 && y0 < HH) ? 1.f : 0.f;
    float vy1 = (y1 >= 0 && y1 < HH) ? 1.f : 0.f;
    int cx0 = min(max(x0, 0), WW - 1), cx1 = min(max(x1, 0), WW - 1);
    int cy0 = min(max(y0, 0), HH - 1), cy1 = min(max(y1, 0), HH - 1);
    off[idx] = make_int4(cy0 * WW + cx0, cy0 * WW + cx1, cy1 * WW + cx0, cy1 * WW + cx1);
    wgt[idx] = make_float4((1.f - wy) * (1.f - wx) * vy0 * vx0,
                           (1.f - wy) * wx        * vy0 * vx1,
                           wy        * (1.f - wx) * vy1 * vx0,
                           wy        * wx         * vy1 * vx1);
    int k = min(max(y0, 0), HH - 2) >> 4;      // rows y0,y0+1 in [16k, 16k+16]
    bkt[idx] = k;
    atomicAdd(&lh[k], 1);
    __syncthreads();
    if (tid < NCHUNK && lh[tid] > 0) atomicAdd(&hist[b * NCHUNK + tid], lh[tid]);
}

// ---------------- kernel 1b: 16-entry prefix scan per batch (tiny) ----------------
__global__ void scan_kernel(const int* __restrict__ hist, int* __restrict__ cs,
                            int* __restrict__ ctr) {
    int b = threadIdx.x;
    if (b < BB) {
        int run = 0;
        for (int k = 0; k < NCHUNK; ++k) {
            cs[b * (NCHUNK + 1) + k] = run;
            ctr[b * NCHUNK + k] = run;
            run += hist[b * NCHUNK + k];
        }
        cs[b * (NCHUNK + 1) + NCHUNK] = run;   // == PP
    }
}

// ---------------- kernel 1c: parallel scatter into buckets ----------------
__global__ __launch_bounds__(256) void scatter_kernel(const int4* __restrict__ off,
                                                      const float4* __restrict__ wgt,
                                                      const int* __restrict__ bkt,
                                                      int* __restrict__ ctr,
                                                      int4* __restrict__ off_s,
                                                      float4* __restrict__ wgt_s) {
    __shared__ int lh[NCHUNK];
    __shared__ int lbase[NCHUNK];
    int tid = threadIdx.x;
    if (tid < NCHUNK) lh[tid] = 0;
    __syncthreads();
    int idx = blockIdx.x * 256 + tid;          // = b*PP + p exactly
    int b = blockIdx.x / PBLK;
    int k = bkt[idx];
    int rank = atomicAdd(&lh[k], 1);
    __syncthreads();
    if (tid < NCHUNK) lbase[tid] = (lh[tid] > 0) ? atomicAdd(&ctr[b * NCHUNK + tid], lh[tid]) : 0;
    __syncthreads();
    int pos = lbase[k] + rank;
    off_s[b * PP + pos] = off[idx];
    wgt_s[b * PP + pos] = wgt[idx];
}

// ---------------- kernel 2: point-sample; one block per (mask, chunk) ----------------
// R0 structure (8 blocks/CU, proven best), but staging via REGISTER loads
// (named float4 -> ds_write_b128) instead of global_load_lds: plain vector
// loads sustain deep HBM queues (R2 evidence: 3.1 TB/s) where the LDS-DMA
// path plateaued at ~1.7 TB/s on HBM-cold data. off/wgt for the first
// compute iteration are prefetched before the barrier.
__global__ __launch_bounds__(256) void sample_kernel(
    const float* __restrict__ pred_masks, const float* __restrict__ tgt_masks,
    const int4* __restrict__ off_s, const float4* __restrict__ wgt_s,
    const int* __restrict__ cs_g,
    bf16_t* __restrict__ OM, bf16_t* __restrict__ SM, bf16_t* __restrict__ TM,
    float* __restrict__ RS_SP, float* __restrict__ RS_S, float* __restrict__ RS_T) {
    int b = blockIdx.z;
    int m = blockIdx.x;  // 0..QQ+TT-1
    int c = blockIdx.y;  // chunk
    int tid = threadIdx.x;
    int wave = tid >> 6, lane = tid & 63;
    __shared__ __align__(16) float rows[17 * WW];
    __shared__ float ra_[4], rb_[4];

    bool is_pred = (m < QQ);
    const float* img;
    bf16_t* row0;
    bf16_t* row1 = nullptr;
    if (is_pred) {
        img  = pred_masks + (size_t)(b * QQ + m) * (HH * WW);
        row0 = OM + (size_t)(b * QQ + m) * PP;
        row1 = SM + (size_t)(b * QQ + m) * PP;
    } else {
        int t = m - QQ;
        img  = tgt_masks + (size_t)(b * TT + t) * (HH * WW);
        row0 = TM + (size_t)(b * TT + t) * PP;
    }

    int base = c * 16;
    const float4* gsrc = (const float4*)(img + base * WW);   // row = 64 float4
    // 4 independent 16B loads per thread (rows wave+4k, col lane), all named regs
    float4 p0 = gsrc[(wave + 0) * 64 + lane];
    float4 p1 = gsrc[(wave + 4) * 64 + lane];
    float4 p2 = gsrc[(wave + 8) * 64 + lane];
    float4 p3 = gsrc[(wave + 12) * 64 + lane];
    float4 p4;
    bool has17 = (c < NCHUNK - 1);
    if (has17 && wave == 0) p4 = gsrc[16 * 64 + lane];       // boundary row

    const int4*   offb = off_s + b * PP;
    const float4* wb   = wgt_s + b * PP;
    const int*    cs   = cs_g + b * (NCHUNK + 1);
    int j1 = cs[c + 1];
    int j = cs[c] + tid;
    int4 o; float4 w;
    if (j < j1) { o = offb[j]; w = wb[j]; }                  // prefetch iter 0

    float4* d = (float4*)rows;
    d[(wave + 0) * 64 + lane] = p0;
    d[(wave + 4) * 64 + lane] = p1;
    d[(wave + 8) * 64 + lane] = p2;
    d[(wave + 12) * 64 + lane] = p3;
    if (has17 && wave == 0) d[16 * 64 + lane] = p4;
    __syncthreads();

    int boff = base * WW;
    float s0 = 0.f, s1 = 0.f;
    while (j < j1) {
        int jn = j + 256;
        int4 on; float4 wn;
        if (jn < j1) { on = offb[jn]; wn = wb[jn]; }         // prefetch next iter
        float v = w.x * rows[o.x - boff] + w.y * rows[o.y - boff] +
                  w.z * rows[o.z - boff] + w.w * rows[o.w - boff];
        row0[j] = (bf16_t)v;
        if (is_pred) {
            float e = __expf(-fabsf(v));
            float r = 1.f / (1.f + e);
            float sg = (v >= 0.f) ? r : e * r;
            row1[j] = (bf16_t)sg;
            s0 += fmaxf(v, 0.f) + __logf(1.f + e);   // stable softplus
            s1 += sg;
        } else {
            s0 += v;
        }
        o = on; w = wn; j = jn;
    }

    for (int sh = 32; sh > 0; sh >>= 1) {
        s0 += __shfl_down(s0, sh, 64);
        s1 += __shfl_down(s1, sh, 64);
    }
    if (lane == 0) { ra_[wave] = s0; rb_[wave] = s1; }
    __syncthreads();
    if (tid == 0) {
        float t0 = ra_[0] + ra_[1] + ra_[2] + ra_[3];
        float t1 = rb_[0] + rb_[1] + rb_[2] + rb_[3];
        if (is_pred) {
            atomicAdd(&RS_SP[b * QQ + m], t0);
            atomicAdd(&RS_S[b * QQ + m], t1);
        } else {
            atomicAdd(&RS_T[b * TT + (m - QQ)], t0);
        }
    }
}

// ---------------- kernel 3: 128x128 dual bf16 MFMA GEMM, split-K ----------------
template<int NS>
__global__ __launch_bounds__(512) void matmul_kernel(
    const bf16_t* __restrict__ OM, const bf16_t* __restrict__ SM, const bf16_t* __restrict__ TM,
    float* __restrict__ A1P, float* __restrict__ A2P) {
    constexpr int KSP = PP / NS;          // 448 (NS=28) or 896 (NS=14)
    constexpr int KST = KSP / 64;
    static_assert(KSP % 64 == 0, "K split must be a multiple of 64");
    int b = blockIdx.z / NS;
    int split = blockIdx.z % NS;
    int m0 = blockIdx.x * 128;
    int n0 = blockIdx.y * 128;
    int tid = threadIdx.x;
    int wave = tid >> 6, lane = tid & 63;
    int lrow = lane & 15, quad = lane >> 4;
    int wm = wave & 3;                     // m-quarter (32 rows)
    int wn = wave >> 2;                    // n-half (64 cols)

    __shared__ __align__(16) bf16_t lds[3 * 128 * 64];   // [A1 | A2 | B], 48 KB

    int k0 = split * KSP;
    int lr8 = lane >> 3;           // row within 8-row group
    int clog = (lane & 7) ^ lr8;   // swizzled logical chunk this lane fetches

    const char* gp[6];
    unsigned lofs[6];
#pragma unroll
    for (int jj = 0; jj < 6; ++jj) {
        int L = wave + jj * 8;     // 48 wave-loads: 3 matrices x 16 row-groups
        int mat = L >> 4, i = L & 15;
        int rb_ = (mat == 2) ? n0 : m0;
        int row = min(rb_ + i * 8 + lr8, (mat == 2) ? (TT - 1) : (QQ - 1));
        const bf16_t* g = (mat == 0) ? OM + (size_t)b * QQ * PP
                        : (mat == 1) ? SM + (size_t)b * QQ * PP
                                     : TM + (size_t)b * TT * PP;
        gp[jj] = (const char*)(g + (size_t)row * PP + k0) + clog * 16;
        lofs[jj] = mat * 8192 + i * 512;   // 8 rows x 64 bf16 per group
    }

    floatx4 acc1[2][4], acc2[2][4];
#pragma unroll
    for (int r = 0; r < 2; ++r)
#pragma unroll
        for (int j = 0; j < 4; ++j) {
            acc1[r][j] = (floatx4){0.f, 0.f, 0.f, 0.f};
            acc2[r][j] = (floatx4){0.f, 0.f, 0.f, 0.f};
        }

    int ar0 = wm * 32 + lrow;              // first 16-row frag
    int ar1 = ar0 + 16;                    // second 16-row frag
    int ax0 = ar0 & 7, ax1 = ar1 & 7;
    for (int s = 0; s < KST; ++s) {
#pragma unroll
        for (int jj = 0; jj < 6; ++jj) {
            gl_lds16(gp[jj], lds + lofs[jj]);
            gp[jj] += 128;   // 64 bf16
        }
        __syncthreads();
#pragma unroll
        for (int kk8 = 0; kk8 <= 4; kk8 += 4) {   // two K=32 halves of BK=64
            bf16x8 a1_0 = *(const bf16x8*)(lds + ar0 * 64 + (((quad + kk8) ^ ax0) << 3));
            bf16x8 a1_1 = *(const bf16x8*)(lds + ar1 * 64 + (((quad + kk8) ^ ax1) << 3));
            bf16x8 a2_0 = *(const bf16x8*)(lds + 8192 + ar0 * 64 + (((quad + kk8) ^ ax0) << 3));
            bf16x8 a2_1 = *(const bf16x8*)(lds + 8192 + ar1 * 64 + (((quad + kk8) ^ ax1) << 3));
#pragma unroll
            for (int j = 0; j < 4; ++j) {
                int br = wn * 64 + j * 16 + lrow;
                bf16x8 vb = *(const bf16x8*)(lds + 16384 + br * 64 + (((quad + kk8) ^ (br & 7)) << 3));
                acc1[0][j] = __builtin_amdgcn_mfma_f32_16x16x32_bf16(a1_0, vb, acc1[0][j], 0, 0, 0);
                acc1[1][j] = __builtin_amdgcn_mfma_f32_16x16x32_bf16(a1_1, vb, acc1[1][j], 0, 0, 0);
                acc2[0][j] = __builtin_amdgcn_mfma_f32_16x16x32_bf16(a2_0, vb, acc2[0][j], 0, 0, 0);
                acc2[1][j] = __builtin_amdgcn_mfma_f32_16x16x32_bf16(a2_1, vb, acc2[1][j], 0, 0, 0);
            }
        }
        __syncthreads();
    }

    // C/D layout: col = lane&15, row = quad*4 + reg
    float* o1 = A1P + (size_t)(b * NS + split) * (QQ * TT);
    float* o2 = A2P + (size_t)(b * NS + split) * (QQ * TT);
#pragma unroll
    for (int r16 = 0; r16 < 2; ++r16) {
        int mrow = m0 + wm * 32 + r16 * 16 + quad * 4;
#pragma unroll
        for (int j = 0; j < 4; ++j) {
            int n = n0 + wn * 64 + j * 16 + lrow;
            if (n < TT) {
#pragma unroll
                for (int r = 0; r < 4; ++r) {
                    int mm = mrow + r;
                    if (mm < QQ) {
                        o1[mm * TT + n] = acc1[r16][j][r];
                        o2[mm * TT + n] = acc2[r16][j][r];
                    }
                }
            }
        }
    }
}

// ---------------- kernel 4: reduce splits + mask/dice/bbox/giou combine ----------------
template<int NS>
__global__ __launch_bounds__(256) void combine_kernel(
    const float* __restrict__ A1P, const float* __restrict__ A2P,
    const float* __restrict__ RS_SP, const float* __restrict__ RS_S, const float* __restrict__ RS_T,
    const float* __restrict__ pred_boxes, const float* __restrict__ tgt_boxes,
    float* __restrict__ out) {
    int idx = blockIdx.x * 256 + threadIdx.x;
    if (idx >= BB * QQ * TT) return;
    int b = idx / (QQ * TT);
    int r = idx - b * (QQ * TT);
    int q = r / TT;
    int t = r - q * TT;

    float a1 = 0.f, a2 = 0.f;
    for (int s = 0; s < NS; ++s) {
        a1 += A1P[(size_t)(b * NS + s) * (QQ * TT) + r];
        a2 += A2P[(size_t)(b * NS + s) * (QQ * TT) + r];
    }
    float cm = (RS_SP[b * QQ + q] - a1) * (1.0f / (float)PP);
    float cd = 1.f - (2.f * a2 + 1.f) / (RS_S[b * QQ + q] + RS_T[b * TT + t] + 1.f);

    const float* pb = pred_boxes + (size_t)(b * QQ + q) * 4;
    const float* tb = tgt_boxes + (size_t)(b * TT + t) * 4;
    float cb = fabsf(pb[0] - tb[0]) + fabsf(pb[1] - tb[1]) +
               fabsf(pb[2] - tb[2]) + fabsf(pb[3] - tb[3]);

    float ax0 = pb[0] - 0.5f * pb[2], ay0 = pb[1] - 0.5f * pb[3];
    float ax1 = pb[0] + 0.5f * pb[2], ay1 = pb[1] + 0.5f * pb[3];
    float bx0 = tb[0] - 0.5f * tb[2], by0 = tb[1] - 0.5f * tb[3];
    float bx1 = tb[0] + 0.5f * tb[2], by1 = tb[1] + 0.5f * tb[3];
    float area_a = (ax1 - ax0) * (ay1 - ay0);
    float area_b = (bx1 - bx0) * (by1 - by0);
    float iw = fmaxf(fminf(ax1, bx1) - fmaxf(ax0, bx0), 0.f);
    float ih = fmaxf(fminf(ay1, by1) - fmaxf(ay0, by0), 0.f);
    float inter = iw * ih;
    float uni = area_a + area_b - inter;
    float iou = inter / uni;
    float ew = fmaxf(ax1, bx1) - fminf(ax0, bx0);
    float eh = fmaxf(ay1, by1) - fminf(ay0, by0);
    float area_e = ew * eh;
    float giou = iou - (area_e - uni) / area_e;

    out[idx] = 5.f * cm + 5.f * cd + 5.f * cb - 2.f * giou;
}

extern "C" void kernel_launch(void* const* d_in, const int* in_sizes, int n_in,
                              void* d_out, int out_size, void* d_ws, size_t ws_size,
                              hipStream_t stream) {
    const float* pred_masks = (const float*)d_in[0];
    const float* tgt_masks  = (const float*)d_in[1];
    const float* pred_boxes = (const float*)d_in[2];
    const float* tgt_boxes  = (const float*)d_in[3];
    const float* pts        = (const float*)d_in[4];

    char* w = (char*)d_ws;
    auto alloc = [&](size_t bytes) -> char* {
        char* r = w;
        w += (bytes + 255) & ~(size_t)255;
        return r;
    };
    int4*   OFF   = (int4*)  alloc((size_t)BB * PP * sizeof(int4));
    float4* WGT   = (float4*)alloc((size_t)BB * PP * sizeof(float4));
    int*    BKT   = (int*)   alloc((size_t)BB * PP * sizeof(int));
    int4*   OFF_S = (int4*)  alloc((size_t)BB * PP * sizeof(int4));
    float4* WGT_S = (float4*)alloc((size_t)BB * PP * sizeof(float4));
    int*    CS    = (int*)   alloc((size_t)BB * (NCHUNK + 1) * sizeof(int));
    bf16_t* OM    = (bf16_t*)alloc((size_t)BB * QQ * PP * 2);
    bf16_t* SM    = (bf16_t*)alloc((size_t)BB * QQ * PP * 2);
    bf16_t* TM    = (bf16_t*)alloc((size_t)BB * TT * PP * 2);
    float*  RS_SP = (float*) alloc((size_t)BB * QQ * 4);
    float*  RS_S  = (float*) alloc((size_t)BB * QQ * 4);
    float*  RS_T  = (float*) alloc((size_t)BB * TT * 4);
    int*    HIST  = (int*)   alloc((size_t)BB * NCHUNK * sizeof(int));
    int*    CTR   = (int*)   alloc((size_t)BB * NCHUNK * sizeof(int));

    // choose split-K factor based on remaining workspace (28 needs +20 MB vs 14)
    size_t used = (size_t)(w - (char*)d_ws);
    size_t per_arr28 = (size_t)BB * 28 * QQ * TT * 4;
    int NS = (ws_size >= used + 2 * per_arr28 + 4096) ? 28 : 14;
    float* A1P = (float*)alloc((size_t)BB * NS * QQ * TT * 4);
    float* A2P = (float*)alloc((size_t)BB * NS * QQ * TT * 4);

    // zero atomic accumulators + histograms (RS_SP..CTR incl. padding)
    hipMemsetAsync(RS_SP, 0, (size_t)((char*)A1P - (char*)RS_SP), stream);

    prep_kernel<<<BB * PBLK, 256, 0, stream>>>(pts, OFF, WGT, BKT, HIST);
    scan_kernel<<<1, 64, 0, stream>>>(HIST, CS, CTR);
    scatter_kernel<<<BB * PBLK, 256, 0, stream>>>(OFF, WGT, BKT, CTR, OFF_S, WGT_S);
    sample_kernel<<<dim3(QQ + TT, NCHUNK, BB), 256, 0, stream>>>(
        pred_masks, tgt_masks, OFF_S, WGT_S, CS, OM, SM, TM, RS_SP, RS_S, RS_T);
    if (NS == 28) {
        matmul_kernel<28><<<dim3(3, 3, BB * 28), 512, 0, stream>>>(OM, SM, TM, A1P, A2P);
        combine_kernel<28><<<(BB * QQ * TT + 255) / 256, 256, 0, stream>>>(
            A1P, A2P, RS_SP, RS_S, RS_T, pred_boxes, tgt_boxes, (float*)d_out);
    } else {
        matmul_kernel<14><<<dim3(3, 3, BB * 14), 512, 0, stream>>>(OM, SM, TM, A1P, A2P);
        combine_kernel<14><<<(BB * QQ * TT + 255) / 256, 256, 0, stream>>>(
            A1P, A2P, RS_SP, RS_S, RS_T, pred_boxes, tgt_boxes, (float*)d_out);
    }
}